// Round 2
// baseline (39.238 us; speedup 1.0000x reference)
//
#include <hip/hip_runtime.h>

namespace {

constexpr int B    = 2;
constexpr int Cc   = 3;                       // final output channels
constexpr int T0   = 5, H0 = 128, W0 = 128;   // input spatial dims
constexpr int PLANE = H0 * W0;                // 16384
constexpr int S_STRIDE = 3 * T0 * PLANE;      // 245760 floats between subband s and s+1
constexpr int TOUT = 17, HOUT = 512, WOUT = 512;
constexpr int NCELLS = B * Cc * T0 * H0 * W0; // 491520

// out[b,c,tau,eta,omega] = sum_s (-1)^popc(s&m) * x[b, 3*s+c, tau>>2, eta>>2, omega>>2]
// s bits: [5]=sT0 [4]=sH0 [3]=sW0 [2]=sT1 [1]=sH1 [0]=sW1
// m bits: [5]=dt0 [4]=dh0 [3]=dw0 [2]=dt1 [1]=dh1 [0]=dw1
//   tau = 4*t0 + 2*dt0 + dt1 (trim: keep tau>=3), eta = 4*h0 + 2*dh0 + dh1,
//   omega = 4*w0 + 2*dw0 + dw1.
__global__ __launch_bounds__(256) void idwt2_wht_kernel(const float* __restrict__ x,
                                                        float* __restrict__ out) {
    const int cell = blockIdx.x * 256 + threadIdx.x;
    const int w0   = cell & (W0 - 1);
    const int h0   = (cell >> 7) & (H0 - 1);
    const int rest = cell >> 14;        // = (b*Cc + c)*T0 + t0
    const int t0   = rest % T0;
    const int bc   = rest / T0;
    const int c    = bc % Cc;
    const int b    = bc / Cc;

    const float* p = x + ((size_t)((b * 192 + c) * T0 + t0) * PLANE
                          + (size_t)h0 * W0 + w0);

    float v[64];
#pragma unroll
    for (int s = 0; s < 64; ++s) v[s] = p[(size_t)s * S_STRIDE];

    // 64-point signed butterfly (Walsh-Hadamard): 6 stages, static indices only.
#pragma unroll
    for (int bit = 0; bit < 6; ++bit) {
        const int k = 1 << bit;
#pragma unroll
        for (int i = 0; i < 64; ++i) {
            if (!(i & k)) {
                const float a  = v[i];
                const float bb = v[i | k];
                v[i]     = a + bb;
                v[i | k] = a - bb;
            }
        }
    }

    float* obase = out + (size_t)(b * Cc + c) * TOUT * HOUT * WOUT;
    const int omega = w0 * 4;

#pragma unroll
    for (int dt0 = 0; dt0 < 2; ++dt0) {
#pragma unroll
        for (int dt1 = 0; dt1 < 2; ++dt1) {
            const int tau = 4 * t0 + 2 * dt0 + dt1;
            if (tau < 3) continue;          // temporal trim; block-uniform branch
            const int taup = tau - 3;
#pragma unroll
            for (int dh0 = 0; dh0 < 2; ++dh0) {
#pragma unroll
                for (int dh1 = 0; dh1 < 2; ++dh1) {
                    const int eta = 4 * h0 + 2 * dh0 + dh1;
                    const int m   = (dt0 << 5) | (dh0 << 4) | (dt1 << 2) | (dh1 << 1);
                    const float4 val = make_float4(v[m], v[m | 1], v[m | 8], v[m | 9]);
                    *reinterpret_cast<float4*>(
                        obase + ((size_t)taup * HOUT + eta) * WOUT + omega) = val;
                }
            }
        }
    }
}

}  // namespace

extern "C" void kernel_launch(void* const* d_in, const int* in_sizes, int n_in,
                              void* d_out, int out_size, void* d_ws, size_t ws_size,
                              hipStream_t stream) {
    const float* x  = (const float*)d_in[0];
    float* out      = (float*)d_out;
    idwt2_wht_kernel<<<NCELLS / 256, 256, 0, stream>>>(x, out);
}

// Round 4
// 38.982 us; speedup vs baseline: 1.0066x; 1.0066x over previous
//
#include <hip/hip_runtime.h>

namespace {

typedef float f32x4 __attribute__((ext_vector_type(4)));

constexpr int B    = 2;
constexpr int Cc   = 3;                       // final output channels
constexpr int T0   = 5, H0 = 128, W0 = 128;   // input spatial dims
constexpr int PLANE = H0 * W0;                // 16384
constexpr int S_STRIDE = 3 * T0 * PLANE;      // 245760 floats between subband s and s+1
constexpr int TOUT = 17, HOUT = 512, WOUT = 512;
constexpr int NCELLS = B * Cc * T0 * H0 * W0; // 491520
constexpr int BLOCK  = 128;                   // 3840 wg = exactly 15 wg/CU (no tail)

// out[b,c,tau,eta,omega] = sum_s (-1)^popc(s&m) * x[b, 3*s+c, tau>>2, eta>>2, omega>>2]
// s bits: [5]=sT0 [4]=sH0 [3]=sW0 [2]=sT1 [1]=sH1 [0]=sW1
// m bits: [5]=dt0 [4]=dh0 [3]=dw0 [2]=dt1 [1]=dh1 [0]=dw1
__global__ __launch_bounds__(BLOCK) void idwt2_wht_kernel(const float* __restrict__ x,
                                                          float* __restrict__ out) {
    const int cell = blockIdx.x * BLOCK + threadIdx.x;
    const int w0   = cell & (W0 - 1);
    const int h0   = (cell >> 7) & (H0 - 1);
    const int rest = cell >> 14;        // = (b*Cc + c)*T0 + t0
    const int t0   = rest % T0;
    const int bc   = rest / T0;
    const int c    = bc % Cc;
    const int b    = bc / Cc;

    const float* p = x + ((size_t)((b * 192 + c) * T0 + t0) * PLANE
                          + (size_t)h0 * W0 + w0);

    float v[64];
#pragma unroll
    for (int s = 0; s < 64; ++s) v[s] = p[(size_t)s * S_STRIDE];

    // 64-point signed butterfly (Walsh-Hadamard): 6 stages, static indices only.
#pragma unroll
    for (int bit = 0; bit < 6; ++bit) {
        const int k = 1 << bit;
#pragma unroll
        for (int i = 0; i < 64; ++i) {
            if (!(i & k)) {
                const float a  = v[i];
                const float bb = v[i | k];
                v[i]     = a + bb;
                v[i | k] = a - bb;
            }
        }
    }

    float* obase = out + (size_t)(b * Cc + c) * TOUT * HOUT * WOUT;
    const int omega = w0 * 4;

#pragma unroll
    for (int dt0 = 0; dt0 < 2; ++dt0) {
#pragma unroll
        for (int dt1 = 0; dt1 < 2; ++dt1) {
            const int tau = 4 * t0 + 2 * dt0 + dt1;
            if (tau < 3) continue;          // temporal trim; block-uniform branch
            const int taup = tau - 3;
#pragma unroll
            for (int dh0 = 0; dh0 < 2; ++dh0) {
#pragma unroll
                for (int dh1 = 0; dh1 < 2; ++dh1) {
                    const int eta = 4 * h0 + 2 * dh0 + dh1;
                    const int m   = (dt0 << 5) | (dh0 << 4) | (dt1 << 2) | (dh1 << 1);
                    f32x4 val;
                    val.x = v[m];
                    val.y = v[m | 1];
                    val.z = v[m | 8];
                    val.w = v[m | 9];
                    // Output is never re-read: stream past L2/L3 (nt flag on
                    // global_store_dwordx4) so the input stays cache-resident.
                    __builtin_nontemporal_store(
                        val, reinterpret_cast<f32x4*>(
                                 obase + ((size_t)taup * HOUT + eta) * WOUT + omega));
                }
            }
        }
    }
}

}  // namespace

extern "C" void kernel_launch(void* const* d_in, const int* in_sizes, int n_in,
                              void* d_out, int out_size, void* d_ws, size_t ws_size,
                              hipStream_t stream) {
    const float* x  = (const float*)d_in[0];
    float* out      = (float*)d_out;
    idwt2_wht_kernel<<<NCELLS / BLOCK, BLOCK, 0, stream>>>(x, out);
}